// Round 1
// 589.252 us; speedup vs baseline: 1.3233x; 1.3233x over previous
//
#include <hip/hip_runtime.h>
#include <hip/hip_bf16.h>

// FeatureInspector: ska (dynamic 3x3 per-group aggregation) -> *roi ->
// grouped conv3x3(G=8)+BN+ReLU -> conv1x1+BN -> out = ska + y
//
// R3: ska vectorized 4-wide (float4 loads for dw/x/roi, float4 out store),
//     y0 stored as bf16 (identical numerics: conv1 converted to bf16 anyway)
//     -> halves y0 write + conv1 read traffic, 4x MLP in ska.
//  conv1: implicit GEMM, 9 shifted K=32 (=ci of group) MFMAs; LDS x-tile
//         [px 18x18][ci 32 pad40] bf16; B-frags in registers from L2.
//  h1 stored bf16 channel-last [b][g][px][ci32] == conv2's A layout.
//  conv2: register GEMM M=64px/block, N=256, K=256; frags straight from
//         global (A L1-hit across waves, B 128KB L2-resident); no LDS.
//
// ws layout (bytes):
//   [0, 67108864)          y0b bf16 ska*roi, planar [b][c][h][w]
//   [67108864, +67108864)  h1t bf16 [b][g][hw][ci32]
//   [134217728, +147456)   w1b bf16 [g][khw][co][ci32]
//   [134365184, +131072)   w2b bf16 [co][ci256]

#define HW 16384
#define EPS 1e-5f

typedef __bf16 bf16x8 __attribute__((ext_vector_type(8)));
typedef short short8 __attribute__((ext_vector_type(8)));
typedef short short4v __attribute__((ext_vector_type(4)));
typedef float floatx4 __attribute__((ext_vector_type(4)));

__device__ __forceinline__ unsigned short f2bf(float f) {
  unsigned u = __builtin_bit_cast(unsigned, f);
  unsigned r = u + 0x7FFFu + ((u >> 16) & 1u);
  return (unsigned short)(r >> 16);
}

__device__ __forceinline__ floatx4 mfma16(short8 a, short8 b, floatx4 c) {
  return __builtin_amdgcn_mfma_f32_16x16x32_bf16(
      __builtin_bit_cast(bf16x8, a), __builtin_bit_cast(bf16x8, b), c, 0, 0, 0);
}

__global__ __launch_bounds__(256) void prepack_w1b(const float* __restrict__ w1,
                                                   unsigned short* __restrict__ w1b) {
  int o = blockIdx.x * 256 + threadIdx.x;      // 73728 = 288 blocks
  int ci  = o & 31;
  int co  = (o >> 5) & 31;
  int khw = (o >> 10) % 9;
  int g   = (o >> 10) / 9;
  w1b[o] = f2bf(w1[((g * 32 + co) * 32 + ci) * 9 + khw]);
}

__global__ __launch_bounds__(256) void prepack_w2b(const float* __restrict__ w2,
                                                   unsigned short* __restrict__ w2b) {
  int o = blockIdx.x * 256 + threadIdx.x;      // 65536 = 256 blocks
  w2b[o] = f2bf(w2[o]);                        // [co][ci] both
}

// 4 outputs (consecutive w) per thread: ska -> d_out (fp32),
// ska*roi -> y0b (bf16). All main loads are dwordx4.
__global__ __launch_bounds__(256) void ska_kernel(const float* __restrict__ x,
                                                  const float* __restrict__ dw,
                                                  const float* __restrict__ roi,
                                                  float* __restrict__ out,
                                                  unsigned short* __restrict__ y0b) {
  int t  = blockIdx.x * 256 + threadIdx.x;     // 8388608 threads = 32768 blocks
  int w0 = (t & 31) << 2;
  int h  = (t >> 5) & 127;
  int c  = (t >> 12) & 255;
  int b  = t >> 20;
  int g  = c >> 5;

  size_t base = ((size_t)(b * 256 + c)) * HW + h * 128 + w0;
  const float* dwb = dw + ((size_t)(b * 8 + g) * 9) * HW + h * 128 + w0;

  // 9 dynamic-weight vectors (streaming, unique)
  floatx4 wv[9];
#pragma unroll
  for (int k = 0; k < 9; ++k) wv[k] = *(const floatx4*)&dwb[k * HW];

  // 3 input rows, 6 columns [w0-1 .. w0+4]
  float xr[3][6];
#pragma unroll
  for (int kh = 0; kh < 3; ++kh) {
    int hh = h + kh - 1;
    if ((unsigned)hh < 128u) {
      const float* xp = x + base + (kh - 1) * 128;
      floatx4 m = *(const floatx4*)xp;
      xr[kh][0] = (w0 > 0) ? xp[-1] : 0.f;
      xr[kh][1] = m[0];
      xr[kh][2] = m[1];
      xr[kh][3] = m[2];
      xr[kh][4] = m[3];
      xr[kh][5] = (w0 < 124) ? xp[4] : 0.f;
    } else {
#pragma unroll
      for (int i = 0; i < 6; ++i) xr[kh][i] = 0.f;
    }
  }

  floatx4 rv = *(const floatx4*)&roi[(size_t)b * HW + h * 128 + w0];

  float s[4] = {0.f, 0.f, 0.f, 0.f};
#pragma unroll
  for (int kh = 0; kh < 3; ++kh) {
#pragma unroll
    for (int kw = 0; kw < 3; ++kw) {
      floatx4 wk = wv[kh * 3 + kw];
#pragma unroll
      for (int j = 0; j < 4; ++j) s[j] += xr[kh][kw + j] * wk[j];
    }
  }

  *(floatx4*)&out[base] = (floatx4){s[0], s[1], s[2], s[3]};
  short4v p;
#pragma unroll
  for (int j = 0; j < 4; ++j) p[j] = (short)f2bf(s[j] * rv[j]);
  *(short4v*)&y0b[base] = p;
}

// Grouped conv3x3 + BN1 + ReLU via MFMA.
// Block: 16x16 px tile of one (b,g); 4 waves; wave = 4 rows x 32 co.
// LDS: x-tile [18*18 px][ci stride 40] bf16 = 25920 B.
__global__ __launch_bounds__(256) void conv1_mfma(
    const unsigned short* __restrict__ y0, const unsigned short* __restrict__ w1b,
    const float* __restrict__ g1, const float* __restrict__ b1,
    const float* __restrict__ m1, const float* __restrict__ v1,
    unsigned short* __restrict__ h1t) {
  __shared__ unsigned short xt[324 * 40];

  int blk  = blockIdx.x;              // 4096 = 8b * 8g * 64 tiles
  int tile = blk & 63;
  int g    = (blk >> 6) & 7;
  int b    = blk >> 9;
  int h0   = (tile >> 3) * 16;
  int w0   = (tile & 7) * 16;
  int tid  = threadIdx.x;

  const unsigned short* xsrc = y0 + ((size_t)(b * 256 + g * 32)) * HW;
  for (int j = tid; j < 324 * 32; j += 256) {
    int ci = j / 324;                 // r-major: 18-elem runs contiguous in gw
    int r  = j - ci * 324;
    int yy = r / 18, xx = r - yy * 18;
    int gh = h0 - 1 + yy, gw = w0 - 1 + xx;
    unsigned short v = 0;
    if ((unsigned)gh < 128u && (unsigned)gw < 128u)
      v = xsrc[ci * HW + gh * 128 + gw];
    xt[r * 40 + ci] = v;
  }

  int wv = tid >> 6, lane = tid & 63, q = lane >> 4, n = lane & 15;

  // B-frags from global (L2-resident, 18 KB/group): [g][khw][co][ci32]
  short8 bf[9][2];
  const unsigned short* wgb = w1b + (size_t)g * 9 * 32 * 32;
#pragma unroll
  for (int khw = 0; khw < 9; ++khw) {
#pragma unroll
    for (int half = 0; half < 2; ++half)
      bf[khw][half] =
          *(const short8*)&wgb[(khw * 32 + half * 16 + n) * 32 + q * 8];
  }

  __syncthreads();

  floatx4 acc[4][2];
#pragma unroll
  for (int r = 0; r < 4; ++r)
#pragma unroll
    for (int half = 0; half < 2; ++half) acc[r][half] = (floatx4){0.f, 0.f, 0.f, 0.f};

#pragma unroll
  for (int r = 0; r < 4; ++r) {
    int row = wv * 4 + r;
#pragma unroll
    for (int khw = 0; khw < 9; ++khw) {
      int kh = khw / 3, kw = khw % 3;
      short8 a = *(const short8*)&xt[((row + kh) * 18 + kw + n) * 40 + q * 8];
      acc[r][0] = mfma16(a, bf[khw][0], acc[r][0]);
      acc[r][1] = mfma16(a, bf[khw][1], acc[r][1]);
    }
  }

  float inv[2], bias[2];
#pragma unroll
  for (int half = 0; half < 2; ++half) {
    int c = g * 32 + half * 16 + n;
    inv[half]  = g1[c] * rsqrtf(v1[c] + EPS);
    bias[half] = b1[c] - m1[c] * inv[half];
  }

  unsigned short* hb = h1t + ((size_t)(b * 8 + g) * HW) * 32;
#pragma unroll
  for (int r = 0; r < 4; ++r) {
    int h = h0 + wv * 4 + r;
#pragma unroll
    for (int half = 0; half < 2; ++half) {
#pragma unroll
      for (int reg = 0; reg < 4; ++reg) {
        int w = w0 + q * 4 + reg;
        float v = fmaxf(acc[r][half][reg] * inv[half] + bias[half], 0.f);
        hb[((size_t)(h * 128 + w)) * 32 + half * 16 + n] = f2bf(v);
      }
    }
  }
}

// 1x1 conv + BN2 + residual. Register GEMM: block = 64 px x 256 co of one b;
// wave = 64 px x 64 co. K = 256 (8 slabs of 32 = one group each). No LDS.
__global__ __launch_bounds__(256) void conv2_mfma(
    const unsigned short* __restrict__ h1t, const unsigned short* __restrict__ w2b,
    const float* __restrict__ g2, const float* __restrict__ b2,
    const float* __restrict__ m2, const float* __restrict__ v2,
    float* __restrict__ out) {
  int blk = blockIdx.x;               // 2048 = 8b * 256 px-tiles
  int b   = blk >> 8;
  int px0 = (blk & 255) * 64;
  int tid = threadIdx.x;
  int wv = tid >> 6, lane = tid & 63, q = lane >> 4, n = lane & 15;

  floatx4 acc[4][4];                  // [mt][nt]
#pragma unroll
  for (int mt = 0; mt < 4; ++mt)
#pragma unroll
    for (int nt = 0; nt < 4; ++nt) acc[mt][nt] = (floatx4){0.f, 0.f, 0.f, 0.f};

  for (int s = 0; s < 8; ++s) {       // K-slab = group s
    short8 a[4];
#pragma unroll
    for (int mt = 0; mt < 4; ++mt)
      a[mt] = *(const short8*)&h1t[((size_t)(b * 8 + s) * HW + px0 + mt * 16 + n) * 32 +
                                   q * 8];
#pragma unroll
    for (int nt = 0; nt < 4; ++nt) {
      int co = wv * 64 + nt * 16 + n;
      short8 bb = *(const short8*)&w2b[co * 256 + s * 32 + q * 8];
#pragma unroll
      for (int mt = 0; mt < 4; ++mt) acc[mt][nt] = mfma16(a[mt], bb, acc[mt][nt]);
    }
  }

#pragma unroll
  for (int nt = 0; nt < 4; ++nt) {
    int co = wv * 64 + nt * 16 + n;
    float inv  = g2[co] * rsqrtf(v2[co] + EPS);
    float bias = b2[co] - m2[co] * inv;
    float* ob = out + (size_t)(b * 256 + co) * HW;
#pragma unroll
    for (int mt = 0; mt < 4; ++mt) {
      int px = px0 + mt * 16 + q * 4;
      float4 sv = *(float4*)&ob[px];
      sv.x += acc[mt][nt][0] * inv + bias;
      sv.y += acc[mt][nt][1] * inv + bias;
      sv.z += acc[mt][nt][2] * inv + bias;
      sv.w += acc[mt][nt][3] * inv + bias;
      *(float4*)&ob[px] = sv;
    }
  }
}

extern "C" void kernel_launch(void* const* d_in, const int* in_sizes, int n_in,
                              void* d_out, int out_size, void* d_ws,
                              size_t ws_size, hipStream_t stream) {
  const float* x   = (const float*)d_in[0];
  const float* dw  = (const float*)d_in[1];
  const float* roi = (const float*)d_in[2];
  const float* w1  = (const float*)d_in[3];
  const float* g1  = (const float*)d_in[4];
  const float* b1  = (const float*)d_in[5];
  const float* m1  = (const float*)d_in[6];
  const float* v1  = (const float*)d_in[7];
  const float* w2  = (const float*)d_in[8];
  const float* g2  = (const float*)d_in[9];
  const float* b2  = (const float*)d_in[10];
  const float* m2  = (const float*)d_in[11];
  const float* v2  = (const float*)d_in[12];
  float* out = (float*)d_out;

  char* ws = (char*)d_ws;
  unsigned short* y0b = (unsigned short*)ws;                 // 67108864 B
  unsigned short* h1t = (unsigned short*)(ws + 67108864);    // 67108864 B
  unsigned short* w1b = (unsigned short*)(ws + 134217728);   // 147456 B
  unsigned short* w2b = (unsigned short*)(ws + 134365184);   // 131072 B

  prepack_w1b<<<288, 256, 0, stream>>>(w1, w1b);
  prepack_w2b<<<256, 256, 0, stream>>>(w2, w2b);
  ska_kernel<<<32768, 256, 0, stream>>>(x, dw, roi, out, y0b);
  conv1_mfma<<<4096, 256, 0, stream>>>(y0b, w1b, g1, b1, m1, v1, h1t);
  conv2_mfma<<<2048, 256, 0, stream>>>(h1t, w2b, g2, b2, m2, v2, out);
}

// Round 2
// 528.617 us; speedup vs baseline: 1.4751x; 1.1147x over previous
//
#include <hip/hip_runtime.h>
#include <hip/hip_bf16.h>

// FeatureInspector: ska (dynamic 3x3 per-group aggregation) -> *roi ->
// grouped conv3x3(G=8)+BN+ReLU -> conv1x1+BN -> out = ska + y
//
// R4: ska restructured: block = 32ci x 32w tile of one (b,g,h) row ->
//     dw/roi loads wave-broadcast across ci (kills the 32x dw re-read),
//     y0b emitted channel-last [b][g][px][ci32] via 2KB LDS transpose
//     with fully coalesced ushort4 stores.
//     conv1: staging now vectorized (short8 global -> ds_write_b128,
//     5/thread instead of 40 scalar 2B loads); epilogue transposed via
//     reused xt LDS -> 4x16B coalesced h1t stores.
//  conv1: implicit GEMM, 9 shifted K=32 MFMAs; LDS x-tile [px 18x18][ci32
//         pad40] bf16; B-frags in registers from L2.
//  conv2: register GEMM M=64px/block, N=256, K=256; frags from global.
//
// ws layout (bytes):
//   [0, 67108864)          y0b bf16 ska*roi, channel-last [b][g][hw][ci32]
//   [67108864, +67108864)  h1t bf16 [b][g][hw][ci32]
//   [134217728, +147456)   w1b bf16 [g][khw][co][ci32]
//   [134365184, +131072)   w2b bf16 [co][ci256]

#define HW 16384
#define EPS 1e-5f

typedef __bf16 bf16x8 __attribute__((ext_vector_type(8)));
typedef short short8 __attribute__((ext_vector_type(8)));
typedef short short4v __attribute__((ext_vector_type(4)));
typedef float floatx4 __attribute__((ext_vector_type(4)));

__device__ __forceinline__ unsigned short f2bf(float f) {
  unsigned u = __builtin_bit_cast(unsigned, f);
  unsigned r = u + 0x7FFFu + ((u >> 16) & 1u);
  return (unsigned short)(r >> 16);
}

__device__ __forceinline__ floatx4 mfma16(short8 a, short8 b, floatx4 c) {
  return __builtin_amdgcn_mfma_f32_16x16x32_bf16(
      __builtin_bit_cast(bf16x8, a), __builtin_bit_cast(bf16x8, b), c, 0, 0, 0);
}

__global__ __launch_bounds__(256) void prepack_w1b(const float* __restrict__ w1,
                                                   unsigned short* __restrict__ w1b) {
  int o = blockIdx.x * 256 + threadIdx.x;      // 73728 = 288 blocks
  int ci  = o & 31;
  int co  = (o >> 5) & 31;
  int khw = (o >> 10) % 9;
  int g   = (o >> 10) / 9;
  w1b[o] = f2bf(w1[((g * 32 + co) * 32 + ci) * 9 + khw]);
}

__global__ __launch_bounds__(256) void prepack_w2b(const float* __restrict__ w2,
                                                   unsigned short* __restrict__ w2b) {
  int o = blockIdx.x * 256 + threadIdx.x;      // 65536 = 256 blocks
  w2b[o] = f2bf(w2[o]);                        // [co][ci] both
}

// Block = one (b,g,h) row, 32ci x 32w tile. Thread: ci = tid>>3, 4 w's.
// dw/roi loads identical across the 8-lane ci groups -> L1 broadcast.
// out (fp32 planar) direct; y0b (bf16 channel-last) via LDS transpose.
__global__ __launch_bounds__(256) void ska_kernel(const float* __restrict__ x,
                                                  const float* __restrict__ dw,
                                                  const float* __restrict__ roi,
                                                  float* __restrict__ out,
                                                  unsigned short* __restrict__ y0b) {
  __shared__ unsigned short tile[32 * 36];     // [w32][ci stride36]

  int blk = blockIdx.x;                        // 32768 = 8b*8g*128h*4wt
  int wt = blk & 3;
  int h  = (blk >> 2) & 127;
  int g  = (blk >> 9) & 7;
  int b  = blk >> 12;
  int tid = threadIdx.x;
  int ci = tid >> 3;
  int wq = tid & 7;
  int w0 = wt * 32 + wq * 4;
  int c  = g * 32 + ci;

  size_t base = ((size_t)(b * 256 + c)) * HW + h * 128 + w0;
  const float* dwb = dw + ((size_t)(b * 8 + g) * 9) * HW + h * 128 + w0;

  floatx4 wv[9];
#pragma unroll
  for (int k = 0; k < 9; ++k) wv[k] = *(const floatx4*)&dwb[k * HW];

  float xr[3][6];
#pragma unroll
  for (int kh = 0; kh < 3; ++kh) {
    int hh = h + kh - 1;
    if ((unsigned)hh < 128u) {
      const float* xp = x + base + (kh - 1) * 128;
      floatx4 m = *(const floatx4*)xp;
      xr[kh][0] = (w0 > 0) ? xp[-1] : 0.f;
      xr[kh][1] = m[0];
      xr[kh][2] = m[1];
      xr[kh][3] = m[2];
      xr[kh][4] = m[3];
      xr[kh][5] = (w0 < 124) ? xp[4] : 0.f;
    } else {
#pragma unroll
      for (int i = 0; i < 6; ++i) xr[kh][i] = 0.f;
    }
  }

  floatx4 rv = *(const floatx4*)&roi[(size_t)b * HW + h * 128 + w0];

  float s[4] = {0.f, 0.f, 0.f, 0.f};
#pragma unroll
  for (int kh = 0; kh < 3; ++kh) {
#pragma unroll
    for (int kw = 0; kw < 3; ++kw) {
      floatx4 wk = wv[kh * 3 + kw];
#pragma unroll
      for (int j = 0; j < 4; ++j) s[j] += xr[kh][kw + j] * wk[j];
    }
  }

  *(floatx4*)&out[base] = (floatx4){s[0], s[1], s[2], s[3]};

  int wl = wq * 4;
#pragma unroll
  for (int j = 0; j < 4; ++j)
    tile[(wl + j) * 36 + ci] = f2bf(s[j] * rv[j]);

  __syncthreads();

  // cooperative coalesced store: 1024 u16 = 2KB contiguous
  unsigned short* dst =
      y0b + ((size_t)(b * 8 + g) * HW + h * 128 + wt * 32) * 32;
  int w = tid >> 3, k = tid & 7;
  *(short4v*)&dst[tid * 4] = *(const short4v*)&tile[w * 36 + k * 4];
}

// Grouped conv3x3 + BN1 + ReLU via MFMA.
// Block: 16x16 px tile of one (b,g); 4 waves; wave = 4 rows x 32 co.
// LDS: x-tile [18*18 px][ci stride 40] bf16 = 25920 B (reused for epilogue).
__global__ __launch_bounds__(256) void conv1_mfma(
    const unsigned short* __restrict__ y0, const unsigned short* __restrict__ w1b,
    const float* __restrict__ g1, const float* __restrict__ b1,
    const float* __restrict__ m1, const float* __restrict__ v1,
    unsigned short* __restrict__ h1t) {
  __shared__ unsigned short xt[324 * 40];

  int blk  = blockIdx.x;              // 4096 = 8b * 8g * 64 tiles
  int tile = blk & 63;
  int g    = (blk >> 6) & 7;
  int b    = blk >> 9;
  int h0   = (tile >> 3) * 16;
  int w0   = (tile & 7) * 16;
  int tid  = threadIdx.x;

  // staging: y0 is [px][ci32] -> 64B contiguous per px; 16B vec per task
  const unsigned short* xsrc = y0 + (size_t)(b * 8 + g) * HW * 32;
  for (int j = tid; j < 1296; j += 256) {     // 324 px * 4 parts
    int r = j >> 2, part = j & 3;
    int yy = r / 18, xx = r - yy * 18;
    int gh = h0 - 1 + yy, gw = w0 - 1 + xx;
    short8 v = (short8){0, 0, 0, 0, 0, 0, 0, 0};
    if ((unsigned)gh < 128u && (unsigned)gw < 128u)
      v = *(const short8*)&xsrc[(size_t)(gh * 128 + gw) * 32 + part * 8];
    *(short8*)&xt[r * 40 + part * 8] = v;
  }

  int wv = tid >> 6, lane = tid & 63, q = lane >> 4, n = lane & 15;

  // B-frags from global (L2-resident, 18 KB/group): [g][khw][co][ci32]
  short8 bf[9][2];
  const unsigned short* wgb = w1b + (size_t)g * 9 * 32 * 32;
#pragma unroll
  for (int khw = 0; khw < 9; ++khw) {
#pragma unroll
    for (int half = 0; half < 2; ++half)
      bf[khw][half] =
          *(const short8*)&wgb[(khw * 32 + half * 16 + n) * 32 + q * 8];
  }

  __syncthreads();

  floatx4 acc[4][2];
#pragma unroll
  for (int r = 0; r < 4; ++r)
#pragma unroll
    for (int half = 0; half < 2; ++half) acc[r][half] = (floatx4){0.f, 0.f, 0.f, 0.f};

#pragma unroll
  for (int r = 0; r < 4; ++r) {
    int row = wv * 4 + r;
#pragma unroll
    for (int khw = 0; khw < 9; ++khw) {
      int kh = khw / 3, kw = khw % 3;
      short8 a = *(const short8*)&xt[((row + kh) * 18 + kw + n) * 40 + q * 8];
      acc[r][0] = mfma16(a, bf[khw][0], acc[r][0]);
      acc[r][1] = mfma16(a, bf[khw][1], acc[r][1]);
    }
  }

  float inv[2], bias[2];
#pragma unroll
  for (int half = 0; half < 2; ++half) {
    int c = g * 32 + half * 16 + n;
    inv[half]  = g1[c] * rsqrtf(v1[c] + EPS);
    bias[half] = b1[c] - m1[c] * inv[half];
  }

  __syncthreads();                     // xt reads done; reuse as [px256][co40]

#pragma unroll
  for (int r = 0; r < 4; ++r) {
    int pr = (wv * 4 + r) * 16;
#pragma unroll
    for (int half = 0; half < 2; ++half) {
      int co = half * 16 + n;
#pragma unroll
      for (int reg = 0; reg < 4; ++reg) {
        int px = pr + q * 4 + reg;
        float v = fmaxf(acc[r][half][reg] * inv[half] + bias[half], 0.f);
        xt[px * 40 + co] = f2bf(v);
      }
    }
  }

  __syncthreads();

  // coalesced h1t store: thread = one px (16x16 tile), 4x16B
  unsigned short* hb = h1t + (size_t)(b * 8 + g) * HW * 32;
  int ph = tid >> 4, pw = tid & 15;
  size_t gp = (size_t)((h0 + ph) * 128 + (w0 + pw)) * 32;
#pragma unroll
  for (int k = 0; k < 4; ++k)
    *(short8*)&hb[gp + k * 8] = *(const short8*)&xt[tid * 40 + k * 8];
}

// 1x1 conv + BN2 + residual. Register GEMM: block = 64 px x 256 co of one b;
// wave = 64 px x 64 co. K = 256 (8 slabs of 32 = one group each). No LDS.
__global__ __launch_bounds__(256) void conv2_mfma(
    const unsigned short* __restrict__ h1t, const unsigned short* __restrict__ w2b,
    const float* __restrict__ g2, const float* __restrict__ b2,
    const float* __restrict__ m2, const float* __restrict__ v2,
    float* __restrict__ out) {
  int blk = blockIdx.x;               // 2048 = 8b * 256 px-tiles
  int b   = blk >> 8;
  int px0 = (blk & 255) * 64;
  int tid = threadIdx.x;
  int wv = tid >> 6, lane = tid & 63, q = lane >> 4, n = lane & 15;

  floatx4 acc[4][4];                  // [mt][nt]
#pragma unroll
  for (int mt = 0; mt < 4; ++mt)
#pragma unroll
    for (int nt = 0; nt < 4; ++nt) acc[mt][nt] = (floatx4){0.f, 0.f, 0.f, 0.f};

  for (int s = 0; s < 8; ++s) {       // K-slab = group s
    short8 a[4];
#pragma unroll
    for (int mt = 0; mt < 4; ++mt)
      a[mt] = *(const short8*)&h1t[((size_t)(b * 8 + s) * HW + px0 + mt * 16 + n) * 32 +
                                   q * 8];
#pragma unroll
    for (int nt = 0; nt < 4; ++nt) {
      int co = wv * 64 + nt * 16 + n;
      short8 bb = *(const short8*)&w2b[co * 256 + s * 32 + q * 8];
#pragma unroll
      for (int mt = 0; mt < 4; ++mt) acc[mt][nt] = mfma16(a[mt], bb, acc[mt][nt]);
    }
  }

#pragma unroll
  for (int nt = 0; nt < 4; ++nt) {
    int co = wv * 64 + nt * 16 + n;
    float inv  = g2[co] * rsqrtf(v2[co] + EPS);
    float bias = b2[co] - m2[co] * inv;
    float* ob = out + (size_t)(b * 256 + co) * HW;
#pragma unroll
    for (int mt = 0; mt < 4; ++mt) {
      int px = px0 + mt * 16 + q * 4;
      float4 sv = *(float4*)&ob[px];
      sv.x += acc[mt][nt][0] * inv + bias;
      sv.y += acc[mt][nt][1] * inv + bias;
      sv.z += acc[mt][nt][2] * inv + bias;
      sv.w += acc[mt][nt][3] * inv + bias;
      *(float4*)&ob[px] = sv;
    }
  }
}

extern "C" void kernel_launch(void* const* d_in, const int* in_sizes, int n_in,
                              void* d_out, int out_size, void* d_ws,
                              size_t ws_size, hipStream_t stream) {
  const float* x   = (const float*)d_in[0];
  const float* dw  = (const float*)d_in[1];
  const float* roi = (const float*)d_in[2];
  const float* w1  = (const float*)d_in[3];
  const float* g1  = (const float*)d_in[4];
  const float* b1  = (const float*)d_in[5];
  const float* m1  = (const float*)d_in[6];
  const float* v1  = (const float*)d_in[7];
  const float* w2  = (const float*)d_in[8];
  const float* g2  = (const float*)d_in[9];
  const float* b2  = (const float*)d_in[10];
  const float* m2  = (const float*)d_in[11];
  const float* v2  = (const float*)d_in[12];
  float* out = (float*)d_out;

  char* ws = (char*)d_ws;
  unsigned short* y0b = (unsigned short*)ws;                 // 67108864 B
  unsigned short* h1t = (unsigned short*)(ws + 67108864);    // 67108864 B
  unsigned short* w1b = (unsigned short*)(ws + 134217728);   // 147456 B
  unsigned short* w2b = (unsigned short*)(ws + 134365184);   // 131072 B

  prepack_w1b<<<288, 256, 0, stream>>>(w1, w1b);
  prepack_w2b<<<256, 256, 0, stream>>>(w2, w2b);
  ska_kernel<<<32768, 256, 0, stream>>>(x, dw, roi, out, y0b);
  conv1_mfma<<<4096, 256, 0, stream>>>(y0b, w1b, g1, b1, m1, v1, h1t);
  conv2_mfma<<<2048, 256, 0, stream>>>(h1t, w2b, g2, b2, m2, v2, out);
}